// Round 4
// baseline (115.990 us; speedup 1.0000x reference)
//
#include <hip/hip_runtime.h>

// LayerStacks round 4: bucket-sorted (64-aligned segments -> wave-uniform
// bucket -> weights via s_load), software-pipelined x prefetch (8 loads in
// flight), weights repacked so each step's quads are contiguous 36-float runs
// (compiler merges to s_load_dwordx16 batches).
//
// d_ws layout:
//   floats [0 .. WBLOB)             packed weights, 6 buckets x BSTRIDE
//   ints   [WBLOB .. WBLOB+16)      cnt[6] (pad 8), cursor[6] (pad 8)
//   ints   [WBLOB+16 .. +16+padcap) perm (bucket-sorted sample ids, -1 = pad)

#define NB 6
#define BSTRIDE 4672
#define O_A    0      // c=0..31: [8x float4 W1b quads | float4 Wout(64+4c)] = 36 floats
#define O_P    1152   // c=0..31: [8x float4 W1pa quads | float4 Wout(192+4c)]
#define O_L2   2304   // j=0..63: [32 W2 row | Wout_j | b2_j | pad2] = 36 floats
#define O_MISC 4608   // [0:8) W1b[:,128], [8:16) W1pa[:,128], [16:24) b1b, [24:32) b1pa
#define O_BOUT 4640
#define WBLOB  (NB * BSTRIDE)

// ---------------- init: zero counters, -1 perm, pack weights -----------------
__global__ __launch_bounds__(256)
void k_init(const float* __restrict__ W1b, const float* __restrict__ b1b,
            const float* __restrict__ W1pa, const float* __restrict__ b1pa,
            const float* __restrict__ W2, const float* __restrict__ b2,
            const float* __restrict__ Wout, const float* __restrict__ bout,
            float* __restrict__ wsF, int* __restrict__ wsI, int B)
{
    const int i0 = blockIdx.x * 256 + threadIdx.x;
    const int stride = gridDim.x * 256;
    const int padcap = B + NB * 64;
    int* perm = wsI + 16;

    for (int i = i0; i < padcap; i += stride) perm[i] = -1;
    if (i0 < 16) wsI[i0] = 0;

    // A / P blobs (L1 weights fused with Wout[64:192] / Wout[192:320])
    for (int e = i0; e < NB * 1152; e += stride) {
        int b = e / 1152, r = e - b * 1152;
        int c = r / 36, t = r - c * 36;
        float va, vp;
        if (t < 32) {
            int j = t >> 2, q = t & 3;
            va = W1b [b * 1032 + j * 129 + c * 4 + q];
            vp = W1pa[b * 1032 + j * 129 + c * 4 + q];
        } else {
            int q = t - 32;
            va = Wout[b * 320 + 64  + c * 4 + q];
            vp = Wout[b * 320 + 192 + c * 4 + q];
        }
        wsF[b * BSTRIDE + O_A + c * 36 + t] = va;
        wsF[b * BSTRIDE + O_P + c * 36 + t] = vp;
    }
    // L2 blob (W2 rows fused with Wout[0:64] and b2)
    for (int e = i0; e < NB * 2304; e += stride) {
        int b = e / 2304, r = e - b * 2304;
        int j = r / 36, t = r - j * 36;
        float v = 0.0f;
        if (t < 32)      v = W2[b * 2048 + j * 32 + t];
        else if (t == 32) v = Wout[b * 320 + j];
        else if (t == 33) v = b2[b * 64 + j];
        wsF[b * BSTRIDE + O_L2 + j * 36 + t] = v;
    }
    for (int e = i0; e < NB * 8; e += stride) {
        int b = e >> 3, j = e & 7;
        wsF[b * BSTRIDE + O_MISC + 0  + j] = W1b [b * 1032 + j * 129 + 128];
        wsF[b * BSTRIDE + O_MISC + 8  + j] = W1pa[b * 1032 + j * 129 + 128];
        wsF[b * BSTRIDE + O_MISC + 16 + j] = b1b[e];
        wsF[b * BSTRIDE + O_MISC + 24 + j] = b1pa[e];
    }
    for (int e = i0; e < NB; e += stride)
        wsF[e * BSTRIDE + O_BOUT] = bout[e];
}

// ---------------- histogram --------------------------------------------------
__global__ __launch_bounds__(256)
void k_hist(const int* __restrict__ ply, int* __restrict__ wsI, int B) {
    __shared__ int lh[NB];
    const int tid = threadIdx.x;
    if (tid < NB) lh[tid] = 0;
    __syncthreads();
    const int s = blockIdx.x * 256 + tid;
    if (s < B) atomicAdd(&lh[ply[s] / 10], 1);
    __syncthreads();
    if (tid < NB) atomicAdd(&wsI[tid], lh[tid]);
}

// ---------------- scan: 64-aligned bucket bases ------------------------------
__global__ void k_scan(int* __restrict__ wsI) {
    if (threadIdx.x == 0) {
        int base = 0;
        for (int b = 0; b < NB; ++b) {
            wsI[8 + b] = base;
            base += (wsI[b] + 63) & ~63;
        }
    }
}

// ---------------- scatter ----------------------------------------------------
__global__ __launch_bounds__(256)
void k_scatter(const int* __restrict__ ply, int* __restrict__ wsI, int B) {
    __shared__ int lh[NB];
    __shared__ int lbase[NB];
    int* cursor = wsI + 8;
    int* perm   = wsI + 16;
    const int tid = threadIdx.x;
    if (tid < NB) lh[tid] = 0;
    __syncthreads();
    const int s = blockIdx.x * 256 + tid;
    int b = 0, lpos = 0;
    if (s < B) { b = ply[s] / 10; lpos = atomicAdd(&lh[b], 1); }
    __syncthreads();
    if (tid < NB) lbase[tid] = atomicAdd(&cursor[tid], lh[tid]);
    __syncthreads();
    if (s < B) perm[lbase[b] + lpos] = s;
}

// ---------------- main -------------------------------------------------------
__global__ __launch_bounds__(256, 4)
void layerstacks_main(const float* __restrict__ x_base,
                      const float* __restrict__ x_pa,
                      const float* __restrict__ mobility,
                      const int*   __restrict__ ply,
                      const float* __restrict__ wsF,
                      const int*   __restrict__ wsI,
                      float* __restrict__ out, int B)
{
    const int padcap = B + NB * 64;
    const int pos = blockIdx.x * 256 + threadIdx.x;
    const int* perm = wsI + 16;

    int s = (pos < padcap) ? perm[pos] : -1;
    const int s0 = __builtin_amdgcn_readfirstlane(s);
    if (s0 < 0) return;                                   // whole wave padding

    const int bu = __builtin_amdgcn_readfirstlane(ply[s0] / 10);
    const float* __restrict__ wp = wsF + bu * BSTRIDE;

    const bool valid = (s >= 0);
    const int su = valid ? s : s0;
    const float mob = fminf(mobility[su] * (7.0f / 255.0f), 1.0f);

    float acc1[16];
    #pragma unroll
    for (int j = 0; j < 8; ++j)
        acc1[j]     = wp[O_MISC + 16 + j] + wp[O_MISC + 0 + j] * mob;
    #pragma unroll
    for (int j = 0; j < 8; ++j)
        acc1[8 + j] = wp[O_MISC + 24 + j] + wp[O_MISC + 8 + j] * mob;

    float accout = wp[O_BOUT];

    const float4* __restrict__ xb4 = reinterpret_cast<const float4*>(x_base + (size_t)su * 128);
    const float4* __restrict__ xp4 = reinterpret_cast<const float4*>(x_pa   + (size_t)su * 128);

    // -------- software-pipelined x_base stream (double-buffered 4x float4) --
    float4 xa[4], xb[4];
    #pragma unroll
    for (int q = 0; q < 4; ++q) xa[q] = xb4[q];

    #pragma unroll
    for (int ch = 0; ch < 8; ++ch) {
        float4* cur = (ch & 1) ? xb : xa;
        float4* nxt = (ch & 1) ? xa : xb;
        if (ch < 7) {
            #pragma unroll
            for (int q = 0; q < 4; ++q) nxt[q] = xb4[(ch + 1) * 4 + q];
        } else {
            #pragma unroll
            for (int q = 0; q < 4; ++q) nxt[q] = xp4[q];   // prefetch pa chunk 0
        }
        #pragma unroll
        for (int q = 0; q < 4; ++q) {
            const int c = ch * 4 + q;
            const float* wc = wp + O_A + c * 36;           // contiguous 36 floats
            const float4 x = cur[q];
            #pragma unroll
            for (int j = 0; j < 8; ++j) {
                const float4 w = *reinterpret_cast<const float4*>(wc + j * 4);
                acc1[j] += w.x * x.x + w.y * x.y + w.z * x.z + w.w * x.w;
            }
            const float4 wo = *reinterpret_cast<const float4*>(wc + 32);
            accout += wo.x * x.x + wo.y * x.y + wo.z * x.z + wo.w * x.w;
        }
    }

    // -------- x_pa stream (chunk 0 already in flight in xa) -----------------
    #pragma unroll
    for (int ch = 0; ch < 8; ++ch) {
        float4* cur = (ch & 1) ? xb : xa;
        float4* nxt = (ch & 1) ? xa : xb;
        if (ch < 7) {
            #pragma unroll
            for (int q = 0; q < 4; ++q) nxt[q] = xp4[(ch + 1) * 4 + q];
        }
        #pragma unroll
        for (int q = 0; q < 4; ++q) {
            const int c = ch * 4 + q;
            const float* wc = wp + O_P + c * 36;
            const float4 x = cur[q];
            #pragma unroll
            for (int j = 0; j < 8; ++j) {
                const float4 w = *reinterpret_cast<const float4*>(wc + j * 4);
                acc1[8 + j] += w.x * x.x + w.y * x.y + w.z * x.z + w.w * x.w;
            }
            const float4 wo = *reinterpret_cast<const float4*>(wc + 32);
            accout += wo.x * x.x + wo.y * x.y + wo.z * x.z + wo.w * x.w;
        }
    }

    // -------- l1c = clip([l1^2 * 255/256, l1], 0, 1) ------------------------
    float l1c[32];
    #pragma unroll
    for (int k = 0; k < 16; ++k) {
        const float v = acc1[k];
        l1c[16 + k] = fminf(fmaxf(v, 0.0f), 1.0f);
        l1c[k] = fminf(v * v * (255.0f / 256.0f), 1.0f);
    }

    // -------- L2 (64x32) fused with Wout[0:64] ------------------------------
    #pragma unroll 4
    for (int j = 0; j < 64; ++j) {
        const float* wr = wp + O_L2 + j * 36;              // contiguous 34 used
        float a = wr[33];                                  // b2[j]
        #pragma unroll
        for (int kq = 0; kq < 8; ++kq) {
            const float4 w = *reinterpret_cast<const float4*>(wr + kq * 4);
            a += w.x * l1c[kq * 4] + w.y * l1c[kq * 4 + 1]
               + w.z * l1c[kq * 4 + 2] + w.w * l1c[kq * 4 + 3];
        }
        a = fminf(fmaxf(a, 0.0f), 1.0f);
        a = a * a * (255.0f / 256.0f);
        accout += wr[32] * a;                              // Wout[j]
    }

    if (valid) out[s] = accout;
}

// ---------------- fallback (round-1 style, self-contained) -------------------
#define FB_BSTR 4580
#define FO_W1B  0
#define FO_W1PA 1056
#define FO_W2   2112
#define FO_WOUT 4160
#define FO_B1B  4480
#define FO_B1PA 4488
#define FO_B2   4496
#define FO_BOUT 4560

__global__ __launch_bounds__(1024, 1)
void layerstacks_fallback(const float* __restrict__ x_base,
                          const float* __restrict__ x_pa,
                          const float* __restrict__ mobility,
                          const int*   __restrict__ ply,
                          const float* __restrict__ W1b,
                          const float* __restrict__ b1b,
                          const float* __restrict__ W1pa,
                          const float* __restrict__ b1pa,
                          const float* __restrict__ W2,
                          const float* __restrict__ b2,
                          const float* __restrict__ Wout,
                          const float* __restrict__ bout,
                          float* __restrict__ out)
{
    __shared__ float lds[NB * FB_BSTR];
    const int tid = threadIdx.x;
    for (int e = tid; e < NB * 1032; e += 1024) {
        int b = e / 1032, r = e - b * 1032;
        int row = r / 129, col = r - row * 129;
        lds[b * FB_BSTR + FO_W1B + row * 132 + col] = W1b[e];
        lds[b * FB_BSTR + FO_W1PA + row * 132 + col] = W1pa[e];
    }
    for (int e = tid; e < NB * 2048; e += 1024) {
        int b = e >> 11, r = e & 2047;
        lds[b * FB_BSTR + FO_W2 + r] = W2[e];
    }
    for (int e = tid; e < NB * 320; e += 1024) {
        int b = e / 320, r = e - b * 320;
        lds[b * FB_BSTR + FO_WOUT + r] = Wout[e];
    }
    if (tid < NB * 8) {
        int b = tid >> 3, r = tid & 7;
        lds[b * FB_BSTR + FO_B1B + r]  = b1b[tid];
        lds[b * FB_BSTR + FO_B1PA + r] = b1pa[tid];
    }
    for (int e = tid; e < NB * 64; e += 1024) {
        int b = e >> 6, r = e & 63;
        lds[b * FB_BSTR + FO_B2 + r] = b2[e];
    }
    if (tid < NB) lds[tid * FB_BSTR + FO_BOUT] = bout[tid];
    __syncthreads();

    const int s = blockIdx.x * 1024 + tid;
    const int idx = ply[s] / 10;
    const float* bk = &lds[idx * FB_BSTR];
    const float mob = fminf(mobility[s] * (7.0f / 255.0f), 1.0f);

    float acc1[16];
    #pragma unroll
    for (int j = 0; j < 8; ++j)
        acc1[j] = bk[FO_B1B + j] + bk[FO_W1B + j * 132 + 128] * mob;
    #pragma unroll
    for (int j = 0; j < 8; ++j)
        acc1[8 + j] = bk[FO_B1PA + j] + bk[FO_W1PA + j * 132 + 128] * mob;
    float accout = bk[FO_BOUT];

    const float4* xb4 = reinterpret_cast<const float4*>(x_base + (size_t)s * 128);
    const float4* xp4 = reinterpret_cast<const float4*>(x_pa   + (size_t)s * 128);
    #pragma unroll 4
    for (int c = 0; c < 32; ++c) {
        const float4 x = xb4[c];
        #pragma unroll
        for (int j = 0; j < 8; ++j) {
            const float4 w = *reinterpret_cast<const float4*>(&bk[FO_W1B + j * 132 + c * 4]);
            acc1[j] += w.x * x.x + w.y * x.y + w.z * x.z + w.w * x.w;
        }
        const float4 wo = *reinterpret_cast<const float4*>(&bk[FO_WOUT + 64 + c * 4]);
        accout += wo.x * x.x + wo.y * x.y + wo.z * x.z + wo.w * x.w;
    }
    #pragma unroll 4
    for (int c = 0; c < 32; ++c) {
        const float4 x = xp4[c];
        #pragma unroll
        for (int j = 0; j < 8; ++j) {
            const float4 w = *reinterpret_cast<const float4*>(&bk[FO_W1PA + j * 132 + c * 4]);
            acc1[8 + j] += w.x * x.x + w.y * x.y + w.z * x.z + w.w * x.w;
        }
        const float4 wo = *reinterpret_cast<const float4*>(&bk[FO_WOUT + 192 + c * 4]);
        accout += wo.x * x.x + wo.y * x.y + wo.z * x.z + wo.w * x.w;
    }
    float l1c[32];
    #pragma unroll
    for (int k = 0; k < 16; ++k) {
        const float v = acc1[k];
        l1c[16 + k] = fminf(fmaxf(v, 0.0f), 1.0f);
        l1c[k] = fminf(v * v * (255.0f / 256.0f), 1.0f);
    }
    #pragma unroll 4
    for (int j = 0; j < 64; ++j) {
        float a = bk[FO_B2 + j];
        #pragma unroll
        for (int k = 0; k < 32; k += 4) {
            const float4 w = *reinterpret_cast<const float4*>(&bk[FO_W2 + j * 32 + k]);
            a += w.x * l1c[k] + w.y * l1c[k + 1] + w.z * l1c[k + 2] + w.w * l1c[k + 3];
        }
        a = fminf(fmaxf(a, 0.0f), 1.0f);
        a = a * a * (255.0f / 256.0f);
        accout += bk[FO_WOUT + j] * a;
    }
    out[s] = accout;
}

extern "C" void kernel_launch(void* const* d_in, const int* in_sizes, int n_in,
                              void* d_out, int out_size, void* d_ws, size_t ws_size,
                              hipStream_t stream) {
    const float* x_base   = (const float*)d_in[0];
    const float* x_pa     = (const float*)d_in[1];
    const float* mobility = (const float*)d_in[2];
    const int*   ply      = (const int*)d_in[3];
    const float* W1b      = (const float*)d_in[4];
    const float* b1b      = (const float*)d_in[5];
    const float* W1pa     = (const float*)d_in[6];
    const float* b1pa     = (const float*)d_in[7];
    const float* W2       = (const float*)d_in[8];
    const float* b2       = (const float*)d_in[9];
    const float* Wout     = (const float*)d_in[10];
    const float* bout     = (const float*)d_in[11];
    float* out = (float*)d_out;

    const int B = in_sizes[3];                      // 262144
    const int padcap = B + NB * 64;
    const size_t ws_needed = (size_t)(WBLOB + 16 + padcap) * sizeof(int);

    if (ws_size >= ws_needed) {
        float* wsF = (float*)d_ws;
        int*   wsI = (int*)d_ws + WBLOB;

        const int blocks256 = (B + 255) / 256;
        k_init<<<256, 256, 0, stream>>>(W1b, b1b, W1pa, b1pa, W2, b2, Wout, bout,
                                        wsF, wsI, B);
        k_hist<<<blocks256, 256, 0, stream>>>(ply, wsI, B);
        k_scan<<<1, 64, 0, stream>>>(wsI);
        k_scatter<<<blocks256, 256, 0, stream>>>(ply, wsI, B);

        const int waves = padcap / 64;
        const int mblocks = (waves + 3) / 4;
        layerstacks_main<<<mblocks, 256, 0, stream>>>(
            x_base, x_pa, mobility, ply, wsF, wsI, out, B);
    } else {
        layerstacks_fallback<<<B / 1024, 1024, 0, stream>>>(
            x_base, x_pa, mobility, ply, W1b, b1b, W1pa, b1pa, W2, b2, Wout, bout, out);
    }
}